// Round 1
// baseline (4512.452 us; speedup 1.0000x reference)
//
#include <hip/hip_runtime.h>
#include <stdint.h>

// PoseRNN: fused = cat(fv,fi) -> 2-layer GRU(768) -> Linear(768,128)+LeakyReLU(0.1) -> Linear(128,6)
// Strategy: single persistent kernel runs BOTH GRU layers pipelined (layer1 lags layer0 by
// one step): 257 rounds instead of 512. 192 WGs = 48 hidden-slices x 2 layers x 2 batch-halves.
// Each WG keeps its Wih/Whh slice (48 rows x 768) in LDS as bf16 for the whole kernel, does the
// x-GEMM and h-GEMM per step with mfma_f32_16x16x32_bf16, gate math in f32, h master in f32 LDS.
// Cross-WG dependency (full h / y0 broadcast) via global bf16 slabs + per-round atomic-counter
// barrier (device scope, release/acquire fences). Two independent barrier groups (batch halves).

typedef __attribute__((ext_vector_type(8))) short bf16x8;   // 8 bf16 in 4 VGPRs
typedef __attribute__((ext_vector_type(4))) float f32x4;

#define H_   768
#define TH3  2304
#define BATCH 64
#define SEQ  256
#define SLAB (BATCH * H_)   /* 49152 elems, one timestep of h/y for all batches */
#define WROW 776            /* padded LDS row stride in ushorts (16B-aligned rows, spreads banks) */
#define NWG_GROUP 96        /* WGs per barrier group (48 slices x 2 layers) */
#define CNT_STRIDE 32       /* ints per round-counter (128B line) */

__device__ __forceinline__ uint16_t f2b(float f) {
  union { float f; uint32_t u; } v; v.f = f;
  uint32_t u = v.u;
  return (uint16_t)((u + 0x7FFFu + ((u >> 16) & 1u)) >> 16);  // RNE
}

__device__ __forceinline__ f32x4 mfma16(bf16x8 a, bf16x8 b, f32x4 c) {
  return __builtin_amdgcn_mfma_f32_16x16x32_bf16(a, b, c, 0, 0, 0);
}

// ---------------- prep: build time-major bf16 X, zero h0 slabs + counters, bf16 W1 -------------
__global__ __launch_bounds__(256) void prep_kernel(
    const float* __restrict__ fv, const float* __restrict__ fi,
    const float* __restrict__ W1,
    uint16_t* __restrict__ Xbf, uint16_t* __restrict__ Y0, uint16_t* __restrict__ Y1,
    int* __restrict__ cnts, uint16_t* __restrict__ W1b)
{
  const int NX = SEQ * SLAB;          // 12,582,912
  const int NY = SLAB;
  const int NC = 2 * 257 * CNT_STRIDE;
  const int NW = 128 * H_;
  const int total = NX + 2 * NY + NC + NW;
  for (int idx = blockIdx.x * blockDim.x + threadIdx.x; idx < total;
       idx += gridDim.x * blockDim.x) {
    if (idx < NX) {
      int s = idx / SLAB;
      int rem = idx - s * SLAB;
      int b = rem / H_;
      int h = rem - b * H_;
      float val = (h < 512) ? fv[((size_t)b * SEQ + s) * 512 + h]
                            : fi[((size_t)b * SEQ + s) * 256 + (h - 512)];
      Xbf[idx] = f2b(val);
    } else if (idx < NX + 2 * NY) {
      int k = idx - NX;
      if (k < NY) Y0[k] = 0; else Y1[k - NY] = 0;
    } else if (idx < NX + 2 * NY + NC) {
      cnts[idx - NX - 2 * NY] = 0;
    } else {
      int k = idx - NX - 2 * NY - NC;
      W1b[k] = f2b(W1[k]);
    }
  }
}

// ---------------- persistent pipelined 2-layer GRU ----------------
__global__ __launch_bounds__(256) void gru_persist(
    const float* __restrict__ Wih, const float* __restrict__ Whh,
    const float* __restrict__ bih, const float* __restrict__ bhh,
    const uint16_t* __restrict__ Xbf, uint16_t* __restrict__ Y0, uint16_t* __restrict__ Y1,
    int* __restrict__ cnts, float* __restrict__ out_hn)
{
  __shared__ __attribute__((aligned(16))) uint16_t Wx[48 * WROW];  // 74,496 B
  __shared__ __attribute__((aligned(16))) uint16_t Wh[48 * WROW];  // 74,496 B
  __shared__ float ghbuf[32 * 48];                                 //  6,144 B
  __shared__ float hmast[32 * 16];                                 //  2,048 B
  __shared__ float bI[48];
  __shared__ float bH[48];

  const int bid   = blockIdx.x;        // 0..191
  const int slice = bid % 48;          // hidden slice: units [slice*16, slice*16+16)
  const int layer = (bid / 48) & 1;    // 0 or 1
  const int bhalf = bid / 96;          // batch half (barrier group)
  const int tid  = threadIdx.x;
  const int lane = tid & 63;
  const int wid  = tid >> 6;           // 4 waves
  const int mblk = wid & 1;            // 16-batch sub-block within the 32-batch half
  const int isGh = wid >> 1;           // waves 0,1 -> x-GEMM; waves 2,3 -> h-GEMM
  const int n16  = lane & 15;
  const int kg   = lane >> 4;

  // --- one-time: weight slices -> LDS bf16; rows ordered [r(16) z(16) n(16)] ---
  const float* wx_g = Wih + (size_t)layer * TH3 * H_;
  const float* wh_g = Whh + (size_t)layer * TH3 * H_;
  for (int idx = tid; idx < 48 * H_; idx += 256) {
    int lr = idx / H_;
    int c  = idx - lr * H_;
    int gate = lr >> 4, j = lr & 15;
    size_t grow = (size_t)(gate * H_ + slice * 16 + j);
    Wx[lr * WROW + c] = f2b(wx_g[grow * H_ + c]);
    Wh[lr * WROW + c] = f2b(wh_g[grow * H_ + c]);
  }
  if (tid < 48) {
    int gate = tid >> 4, j = tid & 15;
    bI[tid] = bih[layer * TH3 + gate * H_ + slice * 16 + j];
    bH[tid] = bhh[layer * TH3 + gate * H_ + slice * 16 + j];
  }
  for (int idx = tid; idx < 32 * 16; idx += 256) hmast[idx] = 0.0f;
  __syncthreads();

  const int batch0 = bhalf * 32;
  int* mycnt = cnts + (size_t)bhalf * 257 * CNT_STRIDE;
  uint16_t* Yown = layer ? Y1 : Y0;

  for (int r = 0; r <= 256; ++r) {
    const bool active = (layer == 0) ? (r < 256) : (r >= 1);
    f32x4 acc0 = {0,0,0,0}, acc1 = {0,0,0,0}, acc2 = {0,0,0,0};
    uint16_t* dst = nullptr;

    if (active) {
      // layer0 step t=r: x=Xbf[r],  h=Y0[r],   writes Y0[r+1]
      // layer1 step t=r-1: x=Y0[r], h=Y1[r-1], writes Y1[r]
      const uint16_t* xs = (layer == 0) ? (Xbf + (size_t)r * SLAB) : (Y0 + (size_t)r * SLAB);
      const uint16_t* hs = (layer == 0) ? (Y0 + (size_t)r * SLAB) : (Y1 + (size_t)(r - 1) * SLAB);
      dst = Yown + (size_t)((layer == 0) ? (r + 1) : r) * SLAB;

      const uint16_t* A  = (isGh ? hs : xs) + (size_t)(batch0 + mblk * 16) * H_;
      const uint16_t* ap = A + (size_t)n16 * H_ + kg * 8;
      const uint16_t* Wl = isGh ? Wh : Wx;
      const uint16_t* bp = Wl + (size_t)n16 * WROW + kg * 8;

      #pragma unroll 4
      for (int ks = 0; ks < 24; ++ks) {
        bf16x8 av  = *reinterpret_cast<const bf16x8*>(ap + ks * 32);
        bf16x8 bv0 = *reinterpret_cast<const bf16x8*>(bp + ks * 32);
        bf16x8 bv1 = *reinterpret_cast<const bf16x8*>(bp + 16 * WROW + ks * 32);
        bf16x8 bv2 = *reinterpret_cast<const bf16x8*>(bp + 32 * WROW + ks * 32);
        acc0 = mfma16(av, bv0, acc0);
        acc1 = mfma16(av, bv1, acc1);
        acc2 = mfma16(av, bv2, acc2);
      }
      if (isGh) {
        #pragma unroll
        for (int q = 0; q < 4; ++q) {
          int bi = mblk * 16 + 4 * kg + q;          // D row = 4*(lane>>4)+q
          ghbuf[bi * 48 +      n16] = acc0[q];
          ghbuf[bi * 48 + 16 + n16] = acc1[q];
          ghbuf[bi * 48 + 32 + n16] = acc2[q];
        }
      }
    }
    __syncthreads();  // gh tiles visible to combine waves

    if (active && !isGh) {
      const bool lastStep = (layer == 0) ? (r == 255) : (r == 256);
      #pragma unroll
      for (int q = 0; q < 4; ++q) {
        int bi = mblk * 16 + 4 * kg + q;
        float ghr = ghbuf[bi * 48 +      n16] + bH[n16];
        float ghz = ghbuf[bi * 48 + 16 + n16] + bH[16 + n16];
        float ghn = ghbuf[bi * 48 + 32 + n16] + bH[32 + n16];
        float gxr = acc0[q] + bI[n16];
        float gxz = acc1[q] + bI[16 + n16];
        float gxn = acc2[q] + bI[32 + n16];
        float rg = 1.0f / (1.0f + __expf(-(gxr + ghr)));
        float zg = 1.0f / (1.0f + __expf(-(gxz + ghz)));
        float ng = tanhf(gxn + rg * ghn);
        float hv = hmast[bi * 16 + n16];
        float hn2 = (1.0f - zg) * ng + zg * hv;
        hmast[bi * 16 + n16] = hn2;
        dst[(size_t)(batch0 + bi) * H_ + slice * 16 + n16] = f2b(hn2);
        if (lastStep)
          out_hn[(size_t)layer * SLAB + (size_t)(batch0 + bi) * H_ + slice * 16 + n16] = hn2;
      }
    }

    if (r < 256) {  // inter-round device barrier (per batch-half group, 96 WGs)
      __syncthreads();
      if (tid == 0) {
        __threadfence();  // release my WG's global writes (agent scope)
        __hip_atomic_fetch_add(&mycnt[r * CNT_STRIDE], 1, __ATOMIC_ACQ_REL,
                               __HIP_MEMORY_SCOPE_AGENT);
        int spins = 0;
        while (__hip_atomic_load(&mycnt[r * CNT_STRIDE], __ATOMIC_ACQUIRE,
                                 __HIP_MEMORY_SCOPE_AGENT) < NWG_GROUP) {
          __builtin_amdgcn_s_sleep(2);
          if (++spins > (1 << 18)) break;  // hang guard; break => absmax fail, not timeout
        }
        __threadfence();  // acquire before next round's reads
      }
      __syncthreads();
    }
  }
}

// ---------------- regressor: pose = LeakyReLU(Y1 @ W1^T + b1) @ W2^T + b2 ----------------
__global__ __launch_bounds__(256) void regressor_kernel(
    const uint16_t* __restrict__ Y1, const uint16_t* __restrict__ W1b,
    const float* __restrict__ b1, const float* __restrict__ W2,
    const float* __restrict__ b2, float* __restrict__ pose)
{
  __shared__ float hdn[64 * 132];
  const int t = blockIdx.x;      // timestep
  const int tid = threadIdx.x;
  const int lane = tid & 63;
  const int wid = tid >> 6;
  const int n16 = lane & 15;
  const int kg = lane >> 4;

  const uint16_t* A  = Y1 + (size_t)(t + 1) * SLAB + (size_t)(wid * 16) * H_;
  const uint16_t* ap = A + (size_t)n16 * H_ + kg * 8;
  const uint16_t* bp = W1b + (size_t)n16 * H_ + kg * 8;

  f32x4 acc[8];
  #pragma unroll
  for (int i = 0; i < 8; ++i) acc[i] = (f32x4){0,0,0,0};

  for (int ks = 0; ks < 24; ++ks) {
    bf16x8 av = *reinterpret_cast<const bf16x8*>(ap + ks * 32);
    #pragma unroll
    for (int nt = 0; nt < 8; ++nt) {
      bf16x8 bv = *reinterpret_cast<const bf16x8*>(bp + (size_t)nt * 16 * H_ + ks * 32);
      acc[nt] = mfma16(av, bv, acc[nt]);
    }
  }
  #pragma unroll
  for (int nt = 0; nt < 8; ++nt) {
    #pragma unroll
    for (int q = 0; q < 4; ++q) {
      int brow = wid * 16 + 4 * kg + q;
      int col  = nt * 16 + n16;
      float v = acc[nt][q] + b1[col];
      v = (v >= 0.0f) ? v : 0.1f * v;   // LeakyReLU(0.1)
      hdn[brow * 132 + col] = v;
    }
  }
  __syncthreads();
  for (int idx = tid; idx < 384; idx += 256) {
    int b = idx / 6, o = idx % 6;
    const float* w2r = W2 + o * 128;
    const float* hr  = &hdn[b * 132];
    float s = b2[o];
    #pragma unroll 4
    for (int c = 0; c < 128; ++c) s += hr[c] * w2r[c];
    pose[(size_t)b * (SEQ * 6) + (size_t)t * 6 + o] = s;
  }
}

extern "C" void kernel_launch(void* const* d_in, const int* in_sizes, int n_in,
                              void* d_out, int out_size, void* d_ws, size_t ws_size,
                              hipStream_t stream) {
  const float* fv  = (const float*)d_in[0];
  const float* fi  = (const float*)d_in[1];
  // d_in[2] = ts (unused by the reference)
  const float* Wih = (const float*)d_in[3];
  const float* Whh = (const float*)d_in[4];
  const float* bih = (const float*)d_in[5];
  const float* bhh = (const float*)d_in[6];
  const float* W1  = (const float*)d_in[7];
  const float* b1  = (const float*)d_in[8];
  const float* W2  = (const float*)d_in[9];
  const float* b2  = (const float*)d_in[10];
  float* out = (float*)d_out;   // [pose: 64*256*6][h_n: 2*64*768]

  char* ws = (char*)d_ws;
  size_t off = 0;
  int* cnts = (int*)(ws + off);
  off += (size_t)2 * 257 * CNT_STRIDE * sizeof(int);
  off = (off + 255) & ~(size_t)255;
  uint16_t* Xbf = (uint16_t*)(ws + off); off += (size_t)SEQ * SLAB * 2;   // 25.2 MB
  uint16_t* Y0  = (uint16_t*)(ws + off); off += (size_t)257 * SLAB * 2;   // 25.3 MB
  uint16_t* Y1  = (uint16_t*)(ws + off); off += (size_t)257 * SLAB * 2;   // 25.3 MB
  uint16_t* W1b = (uint16_t*)(ws + off); off += (size_t)128 * H_ * 2;

  prep_kernel<<<2048, 256, 0, stream>>>(fv, fi, W1, Xbf, Y0, Y1, cnts, W1b);
  gru_persist<<<192, 256, 0, stream>>>(Wih, Whh, bih, bhh, Xbf, Y0, Y1, cnts, out + 98304);
  regressor_kernel<<<SEQ, 256, 0, stream>>>(Y1, W1b, b1, W2, b2, out);
}